// Round 12
// baseline (1416.568 us; speedup 1.0000x reference)
//
#include <hip/hip_runtime.h>

typedef __attribute__((ext_vector_type(8))) short short8;
typedef __attribute__((ext_vector_type(4))) float f32x4;
typedef __attribute__((ext_vector_type(4), aligned(4))) float f32x4u;  // 4B-aligned loads

constexpr int kN = 50000;
constexpr int kE = 300000;
constexpr int kDIN = 963;
constexpr int kH = 256;
constexpr int kNBLK = 6;

__device__ inline unsigned short f2bf(float f) {
    unsigned u = __float_as_uint(f);
    u = u + 0x7FFFu + ((u >> 16) & 1u);   // RTNE
    return (unsigned short)(u >> 16);
}
__device__ inline float bf2f(unsigned short s) {
    return __uint_as_float(((unsigned)s) << 16);
}

__device__ inline void gload_lds16(const void* g, void* l) {
    __builtin_amdgcn_global_load_lds(
        (const __attribute__((address_space(1))) void*)g,
        (__attribute__((address_space(3))) void*)l, 16, 0, 0);
}

// ---------------------------------------------------------------------------
// Layer-1 dual GEMM: [supb | tpreb] = x @ [W1|Wl1]^T  (unchanged from R10)
// ---------------------------------------------------------------------------
__global__ __launch_bounds__(512) void gemm_l1(
    const float* __restrict__ Av, const unsigned short* __restrict__ Bt,
    const float* __restrict__ bias,
    unsigned short* __restrict__ supb, unsigned short* __restrict__ tpreb,
    int M, int Kpad, int Kvalid, int Astride)
{
    __shared__ __align__(16) char smem[49152];
    char* As = smem;             // 128 rows x 128 B
    char* Bs = smem + 16384;     // 256 cols x 128 B

    const int tid = threadIdx.x;
    const int wid = tid >> 6;
    const int lane = tid & 63;
    const int wr = wid >> 2, wc = wid & 3;

    const int nwg = gridDim.x;
    const int q = nwg >> 3, r = nwg & 7;
    const int xcd = blockIdx.x & 7, idx = blockIdx.x >> 3;
    const int t = (xcd < r ? xcd * (q + 1) : r * (q + 1) + (xcd - r) * q) + idx;
    const int r0 = (t >> 1) * 128;
    const int c0 = (t & 1) * 256;

    f32x4 acc[4][4];
#pragma unroll
    for (int i = 0; i < 4; ++i)
#pragma unroll
        for (int j = 0; j < 4; ++j) acc[i][j] = f32x4{0.f, 0.f, 0.f, 0.f};

    const int l_row = lane >> 3;
    const int l_c   = lane & 7;

    for (int k0 = 0; k0 < Kpad; k0 += 64) {
#pragma unroll
        for (int p = 0; p < 4; ++p) {
            int row = wid * 32 + p * 8 + l_row;
            int csw = l_c ^ (row & 7);
            const unsigned short* g = Bt + (long)(c0 + row) * Kpad + k0 + csw * 8;
            gload_lds16(g, Bs + (wid * 32 + p * 8) * 128);
        }
        {   // reg-stage fp32 A -> bf16 LDS, vectorized where fully in-bounds
            const int row = tid >> 2;
            const int kq = tid & 3;
            int grow = r0 + row; if (grow >= M) grow = M - 1;
            const float* ar = Av + (long)grow * Astride;
#pragma unroll
            for (int j = 0; j < 2; ++j) {
                int k16 = kq * 2 + j;
                int kb = k0 + k16 * 8;
                short8 v;
                if (kb + 8 <= Kvalid) {
                    f32x4u f0 = *(const f32x4u*)(ar + kb);
                    f32x4u f1 = *(const f32x4u*)(ar + kb + 4);
#pragma unroll
                    for (int ii = 0; ii < 4; ++ii) {
                        v[ii]     = (short)f2bf(f0[ii]);
                        v[ii + 4] = (short)f2bf(f1[ii]);
                    }
                } else {
#pragma unroll
                    for (int ii = 0; ii < 8; ++ii) {
                        int k = kb + ii;
                        float f = (k < Kvalid) ? ar[k] : 0.f;
                        v[ii] = (short)f2bf(f);
                    }
                }
                *(short8*)(As + row * 128 + ((k16 ^ (row & 7)) << 4)) = v;
            }
        }
        __syncthreads();
#pragma unroll
        for (int kk = 0; kk < 2; ++kk) {
            short8 af[4], bfr[4];
            const int kg = kk * 4 + (lane >> 4);
#pragma unroll
            for (int nr = 0; nr < 4; ++nr) {
                int row = wr * 64 + nr * 16 + (lane & 15);
                af[nr] = *(const short8*)(As + row * 128 + ((kg ^ (row & 7)) << 4));
            }
#pragma unroll
            for (int mc = 0; mc < 4; ++mc) {
                int row = wc * 64 + mc * 16 + (lane & 15);
                bfr[mc] = *(const short8*)(Bs + row * 128 + ((kg ^ (row & 7)) << 4));
            }
#pragma unroll
            for (int mc = 0; mc < 4; ++mc)
#pragma unroll
                for (int nr = 0; nr < 4; ++nr)
                    acc[mc][nr] = __builtin_amdgcn_mfma_f32_16x16x32_bf16(
                        bfr[mc], af[nr], acc[mc][nr], 0, 0, 0);
        }
        __syncthreads();
    }

    const bool isSup = (c0 == 0);
    unsigned short* outp = isSup ? supb : tpreb;
    float* eL = (float*)smem;
    const int wrow = wr * 16 + (lane & 15);
    const int qc = (lane >> 4) << 2;

    for (int nr = 0; nr < 4; ++nr) {
        __syncthreads();
#pragma unroll
        for (int mc = 0; mc < 4; ++mc) {
            const int col = wc * 64 + mc * 16 + qc;
            f32x4 v = acc[mc][nr];
            if (!isSup) v += *(const f32x4*)(bias + col);
            const int c16 = col >> 2;
            *(f32x4*)(eL + wrow * 256 + ((c16 ^ wrow) << 2)) = v;
        }
        __syncthreads();
        const int tr = tid >> 4, j = tid & 15;
        const int gr = r0 + (tr >> 4) * 64 + nr * 16 + (tr & 15);
        if (gr < M) {
#pragma unroll
            for (int p = 0; p < 2; ++p) {
                const int u = j + 16 * p;
                f32x4 lo = *(const f32x4*)(eL + tr * 256 + (((2 * u) ^ tr) << 2));
                f32x4 hi = *(const f32x4*)(eL + tr * 256 + (((2 * u + 1) ^ tr) << 2));
                uint4 pk;
                pk.x = (unsigned)f2bf(lo[0]) | ((unsigned)f2bf(lo[1]) << 16);
                pk.y = (unsigned)f2bf(lo[2]) | ((unsigned)f2bf(lo[3]) << 16);
                pk.z = (unsigned)f2bf(hi[0]) | ((unsigned)f2bf(hi[1]) << 16);
                pk.w = (unsigned)f2bf(hi[2]) | ((unsigned)f2bf(hi[3]) << 16);
                *(uint4*)(outp + (long)gr * 256 + u * 8) = pk;
            }
        }
    }
}

// ---------------------------------------------------------------------------
// Gather-fused block GEMM: y = [act | agg(act)](Mx512) @ Bt^T + bias.
// Bt = [256 out-cols][512 k] bf16 (k<256: Wl cols, k>=256: W cols).
// K-steps 0-3: A staged from act rows (gload_lds).
// K-steps 4-7: A slice COMPUTED in-kernel: 4 threads/row CSR-gather 16 cols
//              each, fp32 accum, bf16 -> swizzled ds_write into As.
// RES 0: out = bf16(relu(y));  RES 1: out = bf16((hbf+relu(y))*0.5)
// RES 2: as 1, plus fp32 x_hidden write.
// Tile 64 rows x 256 cols, 4 waves (1x4), grid 782, XCD-chunked swizzle.
// ---------------------------------------------------------------------------
template<int RES>
__global__ __launch_bounds__(256) void gemm_blk(
    const unsigned short* __restrict__ act,
    const unsigned short* __restrict__ Bt, const float* __restrict__ bias,
    const int* __restrict__ rowptr, const int* __restrict__ e_src,
    const float* __restrict__ e_w,
    const unsigned short* __restrict__ hbf_res,
    unsigned short* __restrict__ outbf, float* __restrict__ hf32)
{
    __shared__ __align__(16) char smem[40960];
    char* As = smem;             // 64 rows x 128 B (64 bf16 k)
    char* Bs = smem + 8192;      // 256 out-cols x 128 B

    const int tid = threadIdx.x;
    const int wid = tid >> 6;      // 0..3 (col group)
    const int lane = tid & 63;

    const int nwg = gridDim.x;
    const int q = nwg >> 3, r = nwg & 7;
    const int xcd = blockIdx.x & 7, idx = blockIdx.x >> 3;
    const int t = (xcd < r ? xcd * (q + 1) : r * (q + 1) + (xcd - r) * q) + idx;
    const int r0 = t * 64;

    f32x4 acc[4][4];
#pragma unroll
    for (int i = 0; i < 4; ++i)
#pragma unroll
        for (int j = 0; j < 4; ++j) acc[i][j] = f32x4{0.f, 0.f, 0.f, 0.f};

    const int l_row = lane >> 3;
    const int l_c   = lane & 7;

    // gather-thread mapping (steps 4-7)
    const int g_row  = tid >> 2;          // 0..63
    const int g_quad = tid & 3;           // 16-col group
    int g_grow = r0 + g_row; if (g_grow >= kN) g_grow = kN - 1;
    const int g_beg = rowptr[g_grow];
    const int g_end = rowptr[g_grow + 1];

    for (int k0 = 0; k0 < 512; k0 += 64) {
        // ---- stage B: 256 out-cols x 64 k (8 gloads/thread)
#pragma unroll
        for (int p = 0; p < 8; ++p) {
            int row = wid * 64 + p * 8 + l_row;
            int csw = l_c ^ (row & 7);
            const unsigned short* g = Bt + (long)row * 512 + k0 + csw * 8;
            gload_lds16(g, Bs + (wid * 64 + p * 8) * 128);
        }
        if (k0 < 256) {
            // ---- stage A from act rows (2 gloads/thread)
#pragma unroll
            for (int p = 0; p < 2; ++p) {
                int row = wid * 16 + p * 8 + l_row;
                int grow = r0 + row; if (grow >= kN) grow = kN - 1;
                int csw = l_c ^ (row & 7);
                const unsigned short* g = act + (long)grow * 256 + k0 + csw * 8;
                gload_lds16(g, As + (wid * 16 + p * 8) * 128);
            }
        } else {
            // ---- fused CSR gather: As[g_row][quad*16..+16) over 64-col slice
            const int cbase = (k0 - 256) + g_quad * 16;
            f32x4 g0 = {0.f,0.f,0.f,0.f}, g1 = {0.f,0.f,0.f,0.f};
            f32x4 g2 = {0.f,0.f,0.f,0.f}, g3 = {0.f,0.f,0.f,0.f};
            for (int b = g_beg; b < g_end; ++b) {
                const int s = e_src[b];
                const float w = e_w[b];
                const unsigned short* ap = act + (long)s * 256 + cbase;
                uint4 v0 = *(const uint4*)(ap);
                uint4 v1 = *(const uint4*)(ap + 8);
                g0[0] += w * bf2f((unsigned short)(v0.x & 0xFFFF));
                g0[1] += w * bf2f((unsigned short)(v0.x >> 16));
                g0[2] += w * bf2f((unsigned short)(v0.y & 0xFFFF));
                g0[3] += w * bf2f((unsigned short)(v0.y >> 16));
                g1[0] += w * bf2f((unsigned short)(v0.z & 0xFFFF));
                g1[1] += w * bf2f((unsigned short)(v0.z >> 16));
                g1[2] += w * bf2f((unsigned short)(v0.w & 0xFFFF));
                g1[3] += w * bf2f((unsigned short)(v0.w >> 16));
                g2[0] += w * bf2f((unsigned short)(v1.x & 0xFFFF));
                g2[1] += w * bf2f((unsigned short)(v1.x >> 16));
                g2[2] += w * bf2f((unsigned short)(v1.y & 0xFFFF));
                g2[3] += w * bf2f((unsigned short)(v1.y >> 16));
                g3[0] += w * bf2f((unsigned short)(v1.z & 0xFFFF));
                g3[1] += w * bf2f((unsigned short)(v1.z >> 16));
                g3[2] += w * bf2f((unsigned short)(v1.w & 0xFFFF));
                g3[3] += w * bf2f((unsigned short)(v1.w >> 16));
            }
            short8 o0, o1;
#pragma unroll
            for (int ii = 0; ii < 4; ++ii) {
                o0[ii]     = (short)f2bf(g0[ii]);
                o0[ii + 4] = (short)f2bf(g1[ii]);
                o1[ii]     = (short)f2bf(g2[ii]);
                o1[ii + 4] = (short)f2bf(g3[ii]);
            }
            const int ch = g_quad * 2;
            *(short8*)(As + g_row * 128 + ((ch       ^ (g_row & 7)) << 4)) = o0;
            *(short8*)(As + g_row * 128 + (((ch + 1) ^ (g_row & 7)) << 4)) = o1;
        }
        __syncthreads();
        // ---- compute: 2 x (8 ds_read_b128 + 16 MFMA per wave)
#pragma unroll
        for (int kk = 0; kk < 2; ++kk) {
            short8 af[4], bfr[4];
            const int kg = kk * 4 + (lane >> 4);
#pragma unroll
            for (int nr = 0; nr < 4; ++nr) {
                int row = nr * 16 + (lane & 15);
                af[nr] = *(const short8*)(As + row * 128 + ((kg ^ (row & 7)) << 4));
            }
#pragma unroll
            for (int mc = 0; mc < 4; ++mc) {
                int row = wid * 64 + mc * 16 + (lane & 15);
                bfr[mc] = *(const short8*)(Bs + row * 128 + ((kg ^ (row & 7)) << 4));
            }
#pragma unroll
            for (int mc = 0; mc < 4; ++mc)
#pragma unroll
                for (int nr = 0; nr < 4; ++nr)
                    acc[mc][nr] = __builtin_amdgcn_mfma_f32_16x16x32_bf16(
                        bfr[mc], af[nr], acc[mc][nr], 0, 0, 0);
        }
        __syncthreads();
    }

    // ---- epilogue: 16-row slabs through LDS, fused bias+relu(+res)(+h)
    float* eL = (float*)smem;                 // 16 x 256 fp32 = 16 KB
    const int row16 = lane & 15;
    const int qc = (lane >> 4) << 2;

    for (int nr = 0; nr < 4; ++nr) {
        __syncthreads();
#pragma unroll
        for (int mc = 0; mc < 4; ++mc) {
            const int col = wid * 64 + mc * 16 + qc;
            f32x4 v = acc[mc][nr] + *(const f32x4*)(bias + col);
            const int c16 = col >> 2;                 // 0..63
            *(f32x4*)(eL + row16 * 256 + ((c16 ^ row16) << 2)) = v;
        }
        __syncthreads();
        const int tr = tid >> 4, j = tid & 15;        // 16 rows x 16 threads
        const int gr = r0 + nr * 16 + tr;
        if (gr < kN) {
#pragma unroll
            for (int p = 0; p < 2; ++p) {
                const int u = j + 16 * p;             // 16B bf16 unit, 0..31
                f32x4 lo = *(const f32x4*)(eL + tr * 256 + (((2 * u) ^ tr) << 2));
                f32x4 hi = *(const f32x4*)(eL + tr * 256 + (((2 * u + 1) ^ tr) << 2));
#pragma unroll
                for (int ii = 0; ii < 4; ++ii) {
                    lo[ii] = fmaxf(lo[ii], 0.f);
                    hi[ii] = fmaxf(hi[ii], 0.f);
                }
                const long gcol = (long)gr * 256 + u * 8;
                if (RES >= 1) {
                    uint4 hv = *(const uint4*)(hbf_res + gcol);
                    lo[0] = (bf2f((unsigned short)(hv.x & 0xFFFF)) + lo[0]) * 0.5f;
                    lo[1] = (bf2f((unsigned short)(hv.x >> 16))    + lo[1]) * 0.5f;
                    lo[2] = (bf2f((unsigned short)(hv.y & 0xFFFF)) + lo[2]) * 0.5f;
                    lo[3] = (bf2f((unsigned short)(hv.y >> 16))    + lo[3]) * 0.5f;
                    hi[0] = (bf2f((unsigned short)(hv.z & 0xFFFF)) + hi[0]) * 0.5f;
                    hi[1] = (bf2f((unsigned short)(hv.z >> 16))    + hi[1]) * 0.5f;
                    hi[2] = (bf2f((unsigned short)(hv.w & 0xFFFF)) + hi[2]) * 0.5f;
                    hi[3] = (bf2f((unsigned short)(hv.w >> 16))    + hi[3]) * 0.5f;
                }
                if (RES == 2) {
                    *(f32x4*)(hf32 + gcol)     = lo;
                    *(f32x4*)(hf32 + gcol + 4) = hi;
                }
                uint4 pk;
                pk.x = (unsigned)f2bf(lo[0]) | ((unsigned)f2bf(lo[1]) << 16);
                pk.y = (unsigned)f2bf(lo[2]) | ((unsigned)f2bf(lo[3]) << 16);
                pk.z = (unsigned)f2bf(hi[0]) | ((unsigned)f2bf(hi[1]) << 16);
                pk.w = (unsigned)f2bf(hi[2]) | ((unsigned)f2bf(hi[3]) << 16);
                *(uint4*)(outbf + gcol) = pk;
            }
        }
    }
}

// ---------------------------------------------------------------------------
// Layer-1 aggregation: hbf = bf16(relu(tpreb + sum ew*supb[src]))
// 16B-lane: one 32-lane half-wave per node, lane owns 8 bf16 cols.
// ---------------------------------------------------------------------------
__global__ __launch_bounds__(256) void agg_l1_kernel(
    const unsigned short* __restrict__ supb, const unsigned short* __restrict__ tpreb,
    const int* __restrict__ rowptr, const int* __restrict__ e_src,
    const float* __restrict__ e_w, unsigned short* __restrict__ outb)
{
    const int tid = threadIdx.x;
    const int sub = tid >> 5;
    const int l   = tid & 31;
    const long node = (long)blockIdx.x * 8 + sub;
    if (node >= kN) return;
    const int c0 = l * 8;

    uint4 tv = *(const uint4*)(tpreb + node * 256 + c0);
    f32x4 a0, a1;
    a0[0] = bf2f((unsigned short)(tv.x & 0xFFFF)); a0[1] = bf2f((unsigned short)(tv.x >> 16));
    a0[2] = bf2f((unsigned short)(tv.y & 0xFFFF)); a0[3] = bf2f((unsigned short)(tv.y >> 16));
    a1[0] = bf2f((unsigned short)(tv.z & 0xFFFF)); a1[1] = bf2f((unsigned short)(tv.z >> 16));
    a1[2] = bf2f((unsigned short)(tv.w & 0xFFFF)); a1[3] = bf2f((unsigned short)(tv.w >> 16));

    int b = rowptr[node];
    const int e = rowptr[node + 1];

#define ACC16(V, W) \
    a0[0] += (W) * bf2f((unsigned short)((V).x & 0xFFFF)); \
    a0[1] += (W) * bf2f((unsigned short)((V).x >> 16));    \
    a0[2] += (W) * bf2f((unsigned short)((V).y & 0xFFFF)); \
    a0[3] += (W) * bf2f((unsigned short)((V).y >> 16));    \
    a1[0] += (W) * bf2f((unsigned short)((V).z & 0xFFFF)); \
    a1[1] += (W) * bf2f((unsigned short)((V).z >> 16));    \
    a1[2] += (W) * bf2f((unsigned short)((V).w & 0xFFFF)); \
    a1[3] += (W) * bf2f((unsigned short)((V).w >> 16));

    for (; b + 4 <= e; b += 4) {
        const int s0 = e_src[b],     s1 = e_src[b + 1];
        const int s2 = e_src[b + 2], s3 = e_src[b + 3];
        const float w0 = e_w[b],     w1 = e_w[b + 1];
        const float w2 = e_w[b + 2], w3 = e_w[b + 3];
        uint4 v0 = *(const uint4*)(supb + (long)s0 * 256 + c0);
        uint4 v1 = *(const uint4*)(supb + (long)s1 * 256 + c0);
        uint4 v2 = *(const uint4*)(supb + (long)s2 * 256 + c0);
        uint4 v3 = *(const uint4*)(supb + (long)s3 * 256 + c0);
        ACC16(v0, w0) ACC16(v1, w1) ACC16(v2, w2) ACC16(v3, w3)
    }
    for (; b < e; ++b) {
        const int s = e_src[b];
        const float w = e_w[b];
        uint4 v = *(const uint4*)(supb + (long)s * 256 + c0);
        ACC16(v, w)
    }
#undef ACC16

#pragma unroll
    for (int ii = 0; ii < 4; ++ii) {
        a0[ii] = fmaxf(a0[ii], 0.f);
        a1[ii] = fmaxf(a1[ii], 0.f);
    }
    uint4 pk;
    pk.x = (unsigned)f2bf(a0[0]) | ((unsigned)f2bf(a0[1]) << 16);
    pk.y = (unsigned)f2bf(a0[2]) | ((unsigned)f2bf(a0[3]) << 16);
    pk.z = (unsigned)f2bf(a1[0]) | ((unsigned)f2bf(a1[1]) << 16);
    pk.w = (unsigned)f2bf(a1[2]) | ((unsigned)f2bf(a1[3]) << 16);
    *(uint4*)(outb + node * 256 + c0) = pk;
}

// ---------------------------------------------------------------------------
// Weight conversion
// ---------------------------------------------------------------------------
__global__ __launch_bounds__(256) void cvt_w1_kernel(
    const float* __restrict__ W1, const float* __restrict__ Wl1,
    unsigned short* __restrict__ out)
{
    int idx = blockIdx.x * 256 + threadIdx.x;       // 512*1024
    if (idx >= 512 * 1024) return;
    int c = idx >> 10, k = idx & 1023;
    float v = 0.f;
    if (k < kDIN) v = (c < 256) ? W1[(long)k * 256 + c] : Wl1[(long)k * 256 + (c - 256)];
    out[idx] = f2bf(v);
}

// blkc layout: [l][out-col c][k] ; k<256 -> Wl[k][c], k>=256 -> W[k-256][c]
__global__ __launch_bounds__(256) void cvt_blk_kernel(
    const float* __restrict__ blkW, const float* __restrict__ blkWl,
    unsigned short* __restrict__ out)
{
    int idx = blockIdx.x * 256 + threadIdx.x;       // 12*256*512
    if (idx >= 12 * 256 * 512) return;
    int l = idx >> 17;
    int rem = idx & 131071;
    int c = rem >> 9, k = rem & 511;
    float v = (k < 256) ? blkWl[((long)l * 256 + k) * 256 + c]
                        : blkW[((long)l * 256 + (k - 256)) * 256 + c];
    out[idx] = f2bf(v);
}

// ---------------------------------------------------------------------------
// CSR build: histogram -> hierarchical exclusive scan -> fill
// ---------------------------------------------------------------------------
__global__ __launch_bounds__(256) void hist_kernel(const int* __restrict__ dst,
                                                   int* __restrict__ counts)
{
    int e = blockIdx.x * 256 + threadIdx.x;
    if (e < kE) atomicAdd(&counts[dst[e]], 1);
}

__global__ __launch_bounds__(1024) void scan1_kernel(
    const int* __restrict__ counts, int* __restrict__ rowptr, int* __restrict__ bsum)
{
    __shared__ int s[1024];
    const int tid = threadIdx.x;
    const int g = blockIdx.x * 1024 + tid;
    const int v = (g < kN) ? counts[g] : 0;
    s[tid] = v; __syncthreads();
    for (int off = 1; off < 1024; off <<= 1) {
        int tv = (tid >= off) ? s[tid - off] : 0;
        __syncthreads();
        s[tid] += tv;
        __syncthreads();
    }
    if (g < kN) rowptr[g] = s[tid] - v;
    if (tid == 1023) bsum[blockIdx.x] = s[1023];
}

__global__ __launch_bounds__(64) void scan2_kernel(int* __restrict__ bsum, int nb)
{
    __shared__ int s[64];
    const int tid = threadIdx.x;
    const int v = (tid < nb) ? bsum[tid] : 0;
    s[tid] = v; __syncthreads();
    for (int off = 1; off < 64; off <<= 1) {
        int tv = (tid >= off) ? s[tid - off] : 0;
        __syncthreads();
        s[tid] += tv;
        __syncthreads();
    }
    if (tid < nb) bsum[tid] = s[tid] - v;
}

__global__ __launch_bounds__(256) void scan3_kernel(
    int* __restrict__ rowptr, const int* __restrict__ bsum, int* __restrict__ cursor)
{
    int g = blockIdx.x * 256 + threadIdx.x;
    if (g < kN) {
        int r = rowptr[g] + bsum[g >> 10];
        rowptr[g] = r;
        cursor[g] = r;
    }
    if (g == 0) rowptr[kN] = kE;
}

__global__ __launch_bounds__(256) void fill_kernel(
    const int* __restrict__ src, const int* __restrict__ dst,
    const float* __restrict__ ew, int* __restrict__ cursor,
    int* __restrict__ e_src, float* __restrict__ e_w)
{
    int e = blockIdx.x * 256 + threadIdx.x;
    if (e >= kE) return;
    int d = dst[e];
    int pos = atomicAdd(&cursor[d], 1);
    e_src[pos] = src[e];
    e_w[pos] = ew[e];
}

// ---------------------------------------------------------------------------
// Final layer (DOUT=3): one wave per row, reads bf16 hidden
// ---------------------------------------------------------------------------
__global__ __launch_bounds__(64) void final_layer_kernel(
    const unsigned short* __restrict__ hbf, const float* __restrict__ W2,
    const float* __restrict__ Wl2, const float* __restrict__ b2,
    float* __restrict__ sup2, float* __restrict__ x_out)
{
    const int row = blockIdx.x;
    const int lane = threadIdx.x;
    const unsigned short* hr = hbf + (long)row * kH;
    float accW[3] = {0.f, 0.f, 0.f};
    float accL[3] = {0.f, 0.f, 0.f};
#pragma unroll
    for (int kb = 0; kb < kH / 64; ++kb) {
        int k = kb * 64 + lane;
        float v = bf2f(hr[k]);
#pragma unroll
        for (int c = 0; c < 3; ++c) {
            accW[c] = fmaf(v, W2[k * 3 + c], accW[c]);
            accL[c] = fmaf(v, Wl2[k * 3 + c], accL[c]);
        }
    }
#pragma unroll
    for (int off = 32; off > 0; off >>= 1) {
#pragma unroll
        for (int c = 0; c < 3; ++c) {
            accW[c] += __shfl_down(accW[c], off);
            accL[c] += __shfl_down(accL[c], off);
        }
    }
    if (lane == 0) {
#pragma unroll
        for (int c = 0; c < 3; ++c) {
            sup2[row * 3 + c] = accW[c];
            x_out[row * 3 + c] = accL[c] + b2[c];
        }
    }
}

__global__ __launch_bounds__(256) void scatter3_kernel(
    const float* __restrict__ sup2, const int* __restrict__ src,
    const int* __restrict__ dst, const float* __restrict__ ew,
    float* __restrict__ x_out)
{
    int e = blockIdx.x * 256 + threadIdx.x;
    if (e >= kE) return;
    int s = src[e];
    int d = dst[e];
    float w = ew[e];
#pragma unroll
    for (int c = 0; c < 3; ++c)
        atomicAdd(&x_out[(long)d * 3 + c], w * sup2[(long)s * 3 + c]);
}

// ---------------------------------------------------------------------------
extern "C" void kernel_launch(void* const* d_in, const int* in_sizes, int n_in,
                              void* d_out, int out_size, void* d_ws, size_t ws_size,
                              hipStream_t stream)
{
    const float* x    = (const float*)d_in[0];
    const int*   src  = (const int*)d_in[1];
    const int*   dst  = (const int*)d_in[2];
    const float* ew   = (const float*)d_in[3];
    const float* W1   = (const float*)d_in[4];
    const float* Wl1  = (const float*)d_in[5];
    const float* b1   = (const float*)d_in[6];
    const float* blkW  = (const float*)d_in[7];
    const float* blkWl = (const float*)d_in[8];
    const float* blkb  = (const float*)d_in[9];
    const float* W2   = (const float*)d_in[10];
    const float* Wl2  = (const float*)d_in[11];
    const float* b2   = (const float*)d_in[12];

    float* out   = (float*)d_out;
    float* x_out = out;                       // N*3
    float* h     = out + (long)kN * 3;        // N*H fp32 = x_hidden output

    // ---- workspace carve-up
    char* w = (char*)d_ws;
    size_t off = 0;
    auto carve = [&](size_t bytes) { char* p = w + off; off = (off + bytes + 255) & ~(size_t)255; return p; };
    unsigned short* supb  = (unsigned short*)carve(12800000UL * 2);
    unsigned short* tpreb = (unsigned short*)carve(12800000UL * 2);  // layer-1 only
    unsigned short* tact  = (unsigned short*)carve(12800000UL * 2);
    unsigned short* hbf   = (unsigned short*)carve(12800000UL * 2);
    unsigned short* w1c   = (unsigned short*)carve(512UL * 1024 * 2);
    unsigned short* blkc  = (unsigned short*)carve(12UL * 256 * 512 * 2);
    int*   e_src  = (int*)carve(kE * 4);
    float* e_w    = (float*)carve(kE * 4);
    int*   counts = (int*)carve(50176 * 4);
    int*   rowptr = (int*)carve(50176 * 4);
    int*   cursor = (int*)carve(50176 * 4);
    int*   bsum   = (int*)carve(64 * 4);
    float* sup2   = (float*)carve((long)kN * 3 * 4);

    // ---- CSR build
    hipMemsetAsync(counts, 0, 50176 * 4, stream);
    hist_kernel<<<(kE + 255) / 256, 256, 0, stream>>>(dst, counts);
    scan1_kernel<<<49, 1024, 0, stream>>>(counts, rowptr, bsum);
    scan2_kernel<<<1, 64, 0, stream>>>(bsum, 49);
    scan3_kernel<<<(kN + 255) / 256, 256, 0, stream>>>(rowptr, bsum, cursor);
    fill_kernel<<<(kE + 255) / 256, 256, 0, stream>>>(src, dst, ew, cursor, e_src, e_w);

    // ---- weight conversion
    cvt_w1_kernel<<<2048, 256, 0, stream>>>(W1, Wl1, w1c);
    cvt_blk_kernel<<<6144, 256, 0, stream>>>(blkW, blkWl, blkc);

    const int l1_grid  = 2 * ((kN + 127) / 128);   // 782
    const int blk_grid = (kN + 63) / 64;           // 782 (64-row tiles)
    const int agg_grid = (kN + 7) / 8;             // 6250

    // ---- Layer 1: hbf = bf16(relu(gconv(x)))
    gemm_l1<<<l1_grid, 512, 0, stream>>>(x, w1c, b1, supb, tpreb,
                                         kN, 1024, kDIN, kDIN);
    agg_l1_kernel<<<agg_grid, 256, 0, stream>>>(supb, tpreb, rowptr, e_src, e_w, hbf);

    // ---- 12 block convs (gather fused into GEMM K>=256 half)
    for (int l = 0; l < 2 * kNBLK; ++l) {
        const unsigned short* act_in = (l & 1) ? tact : hbf;
        unsigned short* act_out      = (l & 1) ? hbf : tact;
        const unsigned short* B = blkc + (long)l * 256 * 512;
        const float* bb = blkb + (long)l * 256;
        if (l & 1) {
            if (l == 2 * kNBLK - 1)
                gemm_blk<2><<<blk_grid, 256, 0, stream>>>(
                    act_in, B, bb, rowptr, e_src, e_w, hbf, act_out, h);
            else
                gemm_blk<1><<<blk_grid, 256, 0, stream>>>(
                    act_in, B, bb, rowptr, e_src, e_w, hbf, act_out, nullptr);
        } else {
            gemm_blk<0><<<blk_grid, 256, 0, stream>>>(
                act_in, B, bb, rowptr, e_src, e_w, nullptr, act_out, nullptr);
        }
    }

    // ---- final layer
    final_layer_kernel<<<kN, 64, 0, stream>>>(hbf, W2, Wl2, b2, sup2, x_out);
    scatter3_kernel<<<(kE + 255) / 256, 256, 0, stream>>>(sup2, src, dst, ew, x_out);
}

// Round 13
// 955.659 us; speedup vs baseline: 1.4823x; 1.4823x over previous
//
#include <hip/hip_runtime.h>

typedef __attribute__((ext_vector_type(8))) short short8;
typedef __attribute__((ext_vector_type(4))) float f32x4;
typedef __attribute__((ext_vector_type(4), aligned(4))) float f32x4u;  // 4B-aligned loads

constexpr int kN = 50000;
constexpr int kE = 300000;
constexpr int kDIN = 963;
constexpr int kH = 256;
constexpr int kNBLK = 6;

__device__ inline unsigned short f2bf(float f) {
    unsigned u = __float_as_uint(f);
    u = u + 0x7FFFu + ((u >> 16) & 1u);   // RTNE
    return (unsigned short)(u >> 16);
}
__device__ inline float bf2f(unsigned short s) {
    return __uint_as_float(((unsigned)s) << 16);
}

__device__ inline void gload_lds16(const void* g, void* l) {
    __builtin_amdgcn_global_load_lds(
        (const __attribute__((address_space(1))) void*)g,
        (__attribute__((address_space(3))) void*)l, 16, 0, 0);
}

// ---------------------------------------------------------------------------
// Layer-1 dual GEMM, single-pass: [supb | tpreb] = x @ [W1|Wl1]^T
// Tile 128 rows x 512 cols (BOTH col-halves per block -> x read ONCE).
// 8 waves (2 row x 4 col); A staged once/K-step; B in two 32KB buffers;
// A-fragments shared across both col-halves. Grid 391, XCD swizzle.
// LDS 80 KB -> 2 blocks/CU.
// ---------------------------------------------------------------------------
__global__ __launch_bounds__(512) void gemm_l1(
    const float* __restrict__ Av, const unsigned short* __restrict__ Bt,
    const float* __restrict__ bias,
    unsigned short* __restrict__ supb, unsigned short* __restrict__ tpreb,
    int M, int Kpad, int Kvalid, int Astride)
{
    __shared__ __align__(16) char smem[81920];
    char* As  = smem;               // 128 rows x 128 B
    char* Bs0 = smem + 16384;       // cols 0-255   x 128 B
    char* Bs1 = smem + 49152;       // cols 256-511 x 128 B

    const int tid = threadIdx.x;
    const int wid = tid >> 6;
    const int lane = tid & 63;
    const int wr = wid >> 2, wc = wid & 3;

    const int nwg = gridDim.x;
    const int q = nwg >> 3, r = nwg & 7;
    const int xcd = blockIdx.x & 7, idx = blockIdx.x >> 3;
    const int t = (xcd < r ? xcd * (q + 1) : r * (q + 1) + (xcd - r) * q) + idx;
    const int r0 = t * 128;

    f32x4 acc[2][4][4];
#pragma unroll
    for (int hf = 0; hf < 2; ++hf)
#pragma unroll
        for (int i = 0; i < 4; ++i)
#pragma unroll
            for (int j = 0; j < 4; ++j) acc[hf][i][j] = f32x4{0.f, 0.f, 0.f, 0.f};

    const int l_row = lane >> 3;
    const int l_c   = lane & 7;

    for (int k0 = 0; k0 < Kpad; k0 += 64) {
        // ---- stage B halves: 4 gloads each per thread
#pragma unroll
        for (int p = 0; p < 4; ++p) {
            int row = wid * 32 + p * 8 + l_row;          // 0..255
            int csw = l_c ^ (row & 7);
            const unsigned short* g0 = Bt + (long)row * Kpad + k0 + csw * 8;
            gload_lds16(g0, Bs0 + (wid * 32 + p * 8) * 128);
            const unsigned short* g1 = Bt + (long)(256 + row) * Kpad + k0 + csw * 8;
            gload_lds16(g1, Bs1 + (wid * 32 + p * 8) * 128);
        }
        {   // reg-stage fp32 A -> bf16 LDS, vectorized where fully in-bounds
            const int row = tid >> 2;
            const int kq = tid & 3;
            int grow = r0 + row; if (grow >= M) grow = M - 1;
            const float* ar = Av + (long)grow * Astride;
#pragma unroll
            for (int j = 0; j < 2; ++j) {
                int k16 = kq * 2 + j;
                int kb = k0 + k16 * 8;
                short8 v;
                if (kb + 8 <= Kvalid) {
                    f32x4u f0 = *(const f32x4u*)(ar + kb);
                    f32x4u f1 = *(const f32x4u*)(ar + kb + 4);
#pragma unroll
                    for (int ii = 0; ii < 4; ++ii) {
                        v[ii]     = (short)f2bf(f0[ii]);
                        v[ii + 4] = (short)f2bf(f1[ii]);
                    }
                } else {
#pragma unroll
                    for (int ii = 0; ii < 8; ++ii) {
                        int k = kb + ii;
                        float f = (k < Kvalid) ? ar[k] : 0.f;
                        v[ii] = (short)f2bf(f);
                    }
                }
                *(short8*)(As + row * 128 + ((k16 ^ (row & 7)) << 4)) = v;
            }
        }
        __syncthreads();
#pragma unroll
        for (int kk = 0; kk < 2; ++kk) {
            const int kg = kk * 4 + (lane >> 4);
            short8 af[4];
#pragma unroll
            for (int nr = 0; nr < 4; ++nr) {
                int row = wr * 64 + nr * 16 + (lane & 15);
                af[nr] = *(const short8*)(As + row * 128 + ((kg ^ (row & 7)) << 4));
            }
#pragma unroll
            for (int hf = 0; hf < 2; ++hf) {
                const char* Bs = hf ? Bs1 : Bs0;
                short8 bfr[4];
#pragma unroll
                for (int mc = 0; mc < 4; ++mc) {
                    int row = wc * 64 + mc * 16 + (lane & 15);
                    bfr[mc] = *(const short8*)(Bs + row * 128 + ((kg ^ (row & 7)) << 4));
                }
#pragma unroll
                for (int mc = 0; mc < 4; ++mc)
#pragma unroll
                    for (int nr = 0; nr < 4; ++nr)
                        acc[hf][mc][nr] = __builtin_amdgcn_mfma_f32_16x16x32_bf16(
                            bfr[mc], af[nr], acc[hf][mc][nr], 0, 0, 0);
            }
        }
        __syncthreads();
    }

    // ---- dual epilogue: half 0 -> supb (no bias), half 1 -> tpreb (+bias)
    float* eL = (float*)smem;
    const int wrow = wr * 16 + (lane & 15);
    const int qc = (lane >> 4) << 2;

#pragma unroll
    for (int hf = 0; hf < 2; ++hf) {
        unsigned short* outp = hf ? tpreb : supb;
        for (int nr = 0; nr < 4; ++nr) {
            __syncthreads();
#pragma unroll
            for (int mc = 0; mc < 4; ++mc) {
                const int col = wc * 64 + mc * 16 + qc;
                f32x4 v = acc[hf][mc][nr];
                if (hf) v += *(const f32x4*)(bias + col);
                const int c16 = col >> 2;
                *(f32x4*)(eL + wrow * 256 + ((c16 ^ wrow) << 2)) = v;
            }
            __syncthreads();
            const int tr = tid >> 4, j = tid & 15;
            const int gr = r0 + (tr >> 4) * 64 + nr * 16 + (tr & 15);
            if (gr < M) {
#pragma unroll
                for (int p = 0; p < 2; ++p) {
                    const int u = j + 16 * p;
                    f32x4 lo = *(const f32x4*)(eL + tr * 256 + (((2 * u) ^ tr) << 2));
                    f32x4 hi = *(const f32x4*)(eL + tr * 256 + (((2 * u + 1) ^ tr) << 2));
                    uint4 pk;
                    pk.x = (unsigned)f2bf(lo[0]) | ((unsigned)f2bf(lo[1]) << 16);
                    pk.y = (unsigned)f2bf(lo[2]) | ((unsigned)f2bf(lo[3]) << 16);
                    pk.z = (unsigned)f2bf(hi[0]) | ((unsigned)f2bf(hi[1]) << 16);
                    pk.w = (unsigned)f2bf(hi[2]) | ((unsigned)f2bf(hi[3]) << 16);
                    *(uint4*)(outp + (long)gr * 256 + u * 8) = pk;
                }
            }
        }
    }
}

// ---------------------------------------------------------------------------
// Block-layer fused GEMM (R11 version): y = [act | xagg](Mx512) @ Bt^T + bias.
// Tile 128x128, 4 waves (2x2), grid 782, XCD-chunked swizzle.
// ---------------------------------------------------------------------------
template<int RES>
__global__ __launch_bounds__(256) void gemm_blk(
    const unsigned short* __restrict__ act, const unsigned short* __restrict__ xagg,
    const unsigned short* __restrict__ Bt, const float* __restrict__ bias,
    const unsigned short* __restrict__ hbf_res,
    unsigned short* __restrict__ outbf, float* __restrict__ hf32)
{
    __shared__ __align__(16) char smem[32768];
    char* As = smem;             // 128 rows x 128 B
    char* Bs = smem + 16384;     // 128 out-cols x 128 B

    const int tid = threadIdx.x;
    const int wid = tid >> 6;      // 0..3
    const int lane = tid & 63;
    const int wr = wid >> 1, wc = wid & 1;

    const int nwg = gridDim.x;
    const int q = nwg >> 3, r = nwg & 7;
    const int xcd = blockIdx.x & 7, idx = blockIdx.x >> 3;
    const int t = (xcd < r ? xcd * (q + 1) : r * (q + 1) + (xcd - r) * q) + idx;
    const int r0 = (t >> 1) * 128;
    const int c0 = (t & 1) * 128;

    f32x4 acc[4][4];
#pragma unroll
    for (int i = 0; i < 4; ++i)
#pragma unroll
        for (int j = 0; j < 4; ++j) acc[i][j] = f32x4{0.f, 0.f, 0.f, 0.f};

    const int l_row = lane >> 3;
    const int l_c   = lane & 7;

    for (int k0 = 0; k0 < 512; k0 += 64) {
#pragma unroll
        for (int p = 0; p < 4; ++p) {
            int row = wid * 32 + p * 8 + l_row;
            int csw = l_c ^ (row & 7);
            const unsigned short* g = Bt + (long)(c0 + row) * 512 + k0 + csw * 8;
            gload_lds16(g, Bs + (wid * 32 + p * 8) * 128);
        }
        const unsigned short* Asrc = (k0 < 256) ? (act + k0) : (xagg + (k0 - 256));
#pragma unroll
        for (int p = 0; p < 4; ++p) {
            int row = wid * 32 + p * 8 + l_row;
            int grow = r0 + row; if (grow >= kN) grow = kN - 1;
            int csw = l_c ^ (row & 7);
            const unsigned short* g = Asrc + (long)grow * 256 + csw * 8;
            gload_lds16(g, As + (wid * 32 + p * 8) * 128);
        }
        __syncthreads();
#pragma unroll
        for (int kk = 0; kk < 2; ++kk) {
            short8 af[4], bfr[4];
            const int kg = kk * 4 + (lane >> 4);
#pragma unroll
            for (int nr = 0; nr < 4; ++nr) {
                int row = wr * 64 + nr * 16 + (lane & 15);
                af[nr] = *(const short8*)(As + row * 128 + ((kg ^ (row & 7)) << 4));
            }
#pragma unroll
            for (int mc = 0; mc < 4; ++mc) {
                int row = wc * 64 + mc * 16 + (lane & 15);
                bfr[mc] = *(const short8*)(Bs + row * 128 + ((kg ^ (row & 7)) << 4));
            }
#pragma unroll
            for (int mc = 0; mc < 4; ++mc)
#pragma unroll
                for (int nr = 0; nr < 4; ++nr)
                    acc[mc][nr] = __builtin_amdgcn_mfma_f32_16x16x32_bf16(
                        bfr[mc], af[nr], acc[mc][nr], 0, 0, 0);
        }
        __syncthreads();
    }

    float* eL = (float*)smem;                 // 32 x 128 fp32 = 16 KB
    const int wrow = wr * 16 + (lane & 15);   // 0..31
    const int qc = (lane >> 4) << 2;

    for (int nr = 0; nr < 4; ++nr) {
        __syncthreads();
#pragma unroll
        for (int mc = 0; mc < 4; ++mc) {
            const int col = wc * 64 + mc * 16 + qc;   // 0..127
            f32x4 v = acc[mc][nr] + *(const f32x4*)(bias + c0 + col);
            const int c16 = col >> 2;                 // 0..31
            *(f32x4*)(eL + wrow * 128 + ((c16 ^ wrow) << 2)) = v;
        }
        __syncthreads();
        const int tr = tid >> 3, j = tid & 7;         // 32 rows x 8 threads
        const int gr = r0 + (tr >> 4) * 64 + nr * 16 + (tr & 15);
        if (gr < kN) {
#pragma unroll
            for (int p = 0; p < 2; ++p) {
                const int u = j + 8 * p;              // 16B bf16 unit, 0..15
                f32x4 lo = *(const f32x4*)(eL + tr * 128 + (((2 * u) ^ tr) << 2));
                f32x4 hi = *(const f32x4*)(eL + tr * 128 + (((2 * u + 1) ^ tr) << 2));
#pragma unroll
                for (int ii = 0; ii < 4; ++ii) {
                    lo[ii] = fmaxf(lo[ii], 0.f);
                    hi[ii] = fmaxf(hi[ii], 0.f);
                }
                const long gcol = (long)gr * 256 + c0 + u * 8;
                if (RES >= 1) {
                    uint4 hv = *(const uint4*)(hbf_res + gcol);
                    lo[0] = (bf2f((unsigned short)(hv.x & 0xFFFF)) + lo[0]) * 0.5f;
                    lo[1] = (bf2f((unsigned short)(hv.x >> 16))    + lo[1]) * 0.5f;
                    lo[2] = (bf2f((unsigned short)(hv.y & 0xFFFF)) + lo[2]) * 0.5f;
                    lo[3] = (bf2f((unsigned short)(hv.y >> 16))    + lo[3]) * 0.5f;
                    hi[0] = (bf2f((unsigned short)(hv.z & 0xFFFF)) + hi[0]) * 0.5f;
                    hi[1] = (bf2f((unsigned short)(hv.z >> 16))    + hi[1]) * 0.5f;
                    hi[2] = (bf2f((unsigned short)(hv.w & 0xFFFF)) + hi[2]) * 0.5f;
                    hi[3] = (bf2f((unsigned short)(hv.w >> 16))    + hi[3]) * 0.5f;
                }
                if (RES == 2) {
                    *(f32x4*)(hf32 + gcol)     = lo;
                    *(f32x4*)(hf32 + gcol + 4) = hi;
                }
                uint4 pk;
                pk.x = (unsigned)f2bf(lo[0]) | ((unsigned)f2bf(lo[1]) << 16);
                pk.y = (unsigned)f2bf(lo[2]) | ((unsigned)f2bf(lo[3]) << 16);
                pk.z = (unsigned)f2bf(hi[0]) | ((unsigned)f2bf(hi[1]) << 16);
                pk.w = (unsigned)f2bf(hi[2]) | ((unsigned)f2bf(hi[3]) << 16);
                *(uint4*)(outbf + gcol) = pk;
            }
        }
    }
}

// ---------------------------------------------------------------------------
// 16B-lane CSR gather (R11 version). One 32-lane half-wave per node.
// MODE 0: xagg = bf16(sum ew*act[src])
// MODE 1: hbf  = bf16(relu(tpreb + sum ew*supb[src]))   (layer 1)
// ---------------------------------------------------------------------------
template<int MODE>
__global__ __launch_bounds__(256) void agg16_kernel(
    const unsigned short* __restrict__ srcbuf, const unsigned short* __restrict__ tpreb,
    const int* __restrict__ rowptr, const int* __restrict__ e_src,
    const float* __restrict__ e_w, unsigned short* __restrict__ outb)
{
    const int tid = threadIdx.x;
    const int sub = tid >> 5;          // 0..7 half-wave in block
    const int l   = tid & 31;
    const long node = (long)blockIdx.x * 8 + sub;
    if (node >= kN) return;
    const int c0 = l * 8;              // 8 cols = 16 B

    f32x4 a0 = {0.f, 0.f, 0.f, 0.f}, a1 = {0.f, 0.f, 0.f, 0.f};
    if (MODE == 1) {
        uint4 tv = *(const uint4*)(tpreb + node * 256 + c0);
        a0[0] = bf2f((unsigned short)(tv.x & 0xFFFF)); a0[1] = bf2f((unsigned short)(tv.x >> 16));
        a0[2] = bf2f((unsigned short)(tv.y & 0xFFFF)); a0[3] = bf2f((unsigned short)(tv.y >> 16));
        a1[0] = bf2f((unsigned short)(tv.z & 0xFFFF)); a1[1] = bf2f((unsigned short)(tv.z >> 16));
        a1[2] = bf2f((unsigned short)(tv.w & 0xFFFF)); a1[3] = bf2f((unsigned short)(tv.w >> 16));
    }

    int b = rowptr[node];
    const int e = rowptr[node + 1];

#define ACC16(V, W) \
    a0[0] += (W) * bf2f((unsigned short)((V).x & 0xFFFF)); \
    a0[1] += (W) * bf2f((unsigned short)((V).x >> 16));    \
    a0[2] += (W) * bf2f((unsigned short)((V).y & 0xFFFF)); \
    a0[3] += (W) * bf2f((unsigned short)((V).y >> 16));    \
    a1[0] += (W) * bf2f((unsigned short)((V).z & 0xFFFF)); \
    a1[1] += (W) * bf2f((unsigned short)((V).z >> 16));    \
    a1[2] += (W) * bf2f((unsigned short)((V).w & 0xFFFF)); \
    a1[3] += (W) * bf2f((unsigned short)((V).w >> 16));

    for (; b + 4 <= e; b += 4) {
        const int s0 = e_src[b],     s1 = e_src[b + 1];
        const int s2 = e_src[b + 2], s3 = e_src[b + 3];
        const float w0 = e_w[b],     w1 = e_w[b + 1];
        const float w2 = e_w[b + 2], w3 = e_w[b + 3];
        uint4 v0 = *(const uint4*)(srcbuf + (long)s0 * 256 + c0);
        uint4 v1 = *(const uint4*)(srcbuf + (long)s1 * 256 + c0);
        uint4 v2 = *(const uint4*)(srcbuf + (long)s2 * 256 + c0);
        uint4 v3 = *(const uint4*)(srcbuf + (long)s3 * 256 + c0);
        ACC16(v0, w0) ACC16(v1, w1) ACC16(v2, w2) ACC16(v3, w3)
    }
    for (; b < e; ++b) {
        const int s = e_src[b];
        const float w = e_w[b];
        uint4 v = *(const uint4*)(srcbuf + (long)s * 256 + c0);
        ACC16(v, w)
    }
#undef ACC16

    if (MODE == 1) {
#pragma unroll
        for (int ii = 0; ii < 4; ++ii) {
            a0[ii] = fmaxf(a0[ii], 0.f);
            a1[ii] = fmaxf(a1[ii], 0.f);
        }
    }
    uint4 pk;
    pk.x = (unsigned)f2bf(a0[0]) | ((unsigned)f2bf(a0[1]) << 16);
    pk.y = (unsigned)f2bf(a0[2]) | ((unsigned)f2bf(a0[3]) << 16);
    pk.z = (unsigned)f2bf(a1[0]) | ((unsigned)f2bf(a1[1]) << 16);
    pk.w = (unsigned)f2bf(a1[2]) | ((unsigned)f2bf(a1[3]) << 16);
    *(uint4*)(outb + node * 256 + c0) = pk;
}

// ---------------------------------------------------------------------------
// Weight conversion
// ---------------------------------------------------------------------------
__global__ __launch_bounds__(256) void cvt_w1_kernel(
    const float* __restrict__ W1, const float* __restrict__ Wl1,
    unsigned short* __restrict__ out)
{
    int idx = blockIdx.x * 256 + threadIdx.x;       // 512*1024
    if (idx >= 512 * 1024) return;
    int c = idx >> 10, k = idx & 1023;
    float v = 0.f;
    if (k < kDIN) v = (c < 256) ? W1[(long)k * 256 + c] : Wl1[(long)k * 256 + (c - 256)];
    out[idx] = f2bf(v);
}

// blkc layout: [l][out-col c][k] ; k<256 -> Wl[k][c], k>=256 -> W[k-256][c]
__global__ __launch_bounds__(256) void cvt_blk_kernel(
    const float* __restrict__ blkW, const float* __restrict__ blkWl,
    unsigned short* __restrict__ out)
{
    int idx = blockIdx.x * 256 + threadIdx.x;       // 12*256*512
    if (idx >= 12 * 256 * 512) return;
    int l = idx >> 17;
    int rem = idx & 131071;
    int c = rem >> 9, k = rem & 511;
    float v = (k < 256) ? blkWl[((long)l * 256 + k) * 256 + c]
                        : blkW[((long)l * 256 + (k - 256)) * 256 + c];
    out[idx] = f2bf(v);
}

// ---------------------------------------------------------------------------
// CSR build: histogram -> hierarchical exclusive scan -> fill
// ---------------------------------------------------------------------------
__global__ __launch_bounds__(256) void hist_kernel(const int* __restrict__ dst,
                                                   int* __restrict__ counts)
{
    int e = blockIdx.x * 256 + threadIdx.x;
    if (e < kE) atomicAdd(&counts[dst[e]], 1);
}

__global__ __launch_bounds__(1024) void scan1_kernel(
    const int* __restrict__ counts, int* __restrict__ rowptr, int* __restrict__ bsum)
{
    __shared__ int s[1024];
    const int tid = threadIdx.x;
    const int g = blockIdx.x * 1024 + tid;
    const int v = (g < kN) ? counts[g] : 0;
    s[tid] = v; __syncthreads();
    for (int off = 1; off < 1024; off <<= 1) {
        int tv = (tid >= off) ? s[tid - off] : 0;
        __syncthreads();
        s[tid] += tv;
        __syncthreads();
    }
    if (g < kN) rowptr[g] = s[tid] - v;
    if (tid == 1023) bsum[blockIdx.x] = s[1023];
}

__global__ __launch_bounds__(64) void scan2_kernel(int* __restrict__ bsum, int nb)
{
    __shared__ int s[64];
    const int tid = threadIdx.x;
    const int v = (tid < nb) ? bsum[tid] : 0;
    s[tid] = v; __syncthreads();
    for (int off = 1; off < 64; off <<= 1) {
        int tv = (tid >= off) ? s[tid - off] : 0;
        __syncthreads();
        s[tid] += tv;
        __syncthreads();
    }
    if (tid < nb) bsum[tid] = s[tid] - v;
}

__global__ __launch_bounds__(256) void scan3_kernel(
    int* __restrict__ rowptr, const int* __restrict__ bsum, int* __restrict__ cursor)
{
    int g = blockIdx.x * 256 + threadIdx.x;
    if (g < kN) {
        int r = rowptr[g] + bsum[g >> 10];
        rowptr[g] = r;
        cursor[g] = r;
    }
    if (g == 0) rowptr[kN] = kE;
}

__global__ __launch_bounds__(256) void fill_kernel(
    const int* __restrict__ src, const int* __restrict__ dst,
    const float* __restrict__ ew, int* __restrict__ cursor,
    int* __restrict__ e_src, float* __restrict__ e_w)
{
    int e = blockIdx.x * 256 + threadIdx.x;
    if (e >= kE) return;
    int d = dst[e];
    int pos = atomicAdd(&cursor[d], 1);
    e_src[pos] = src[e];
    e_w[pos] = ew[e];
}

// ---------------------------------------------------------------------------
// Final layer (DOUT=3): one wave per row, reads bf16 hidden
// ---------------------------------------------------------------------------
__global__ __launch_bounds__(64) void final_layer_kernel(
    const unsigned short* __restrict__ hbf, const float* __restrict__ W2,
    const float* __restrict__ Wl2, const float* __restrict__ b2,
    float* __restrict__ sup2, float* __restrict__ x_out)
{
    const int row = blockIdx.x;
    const int lane = threadIdx.x;
    const unsigned short* hr = hbf + (long)row * kH;
    float accW[3] = {0.f, 0.f, 0.f};
    float accL[3] = {0.f, 0.f, 0.f};
#pragma unroll
    for (int kb = 0; kb < kH / 64; ++kb) {
        int k = kb * 64 + lane;
        float v = bf2f(hr[k]);
#pragma unroll
        for (int c = 0; c < 3; ++c) {
            accW[c] = fmaf(v, W2[k * 3 + c], accW[c]);
            accL[c] = fmaf(v, Wl2[k * 3 + c], accL[c]);
        }
    }
#pragma unroll
    for (int off = 32; off > 0; off >>= 1) {
#pragma unroll
        for (int c = 0; c < 3; ++c) {
            accW[c] += __shfl_down(accW[c], off);
            accL[c] += __shfl_down(accL[c], off);
        }
    }
    if (lane == 0) {
#pragma unroll
        for (int c = 0; c < 3; ++c) {
            sup2[row * 3 + c] = accW[c];
            x_out[row * 3 + c] = accL[c] + b2[c];
        }
    }
}

__global__ __launch_bounds__(256) void scatter3_kernel(
    const float* __restrict__ sup2, const int* __restrict__ src,
    const int* __restrict__ dst, const float* __restrict__ ew,
    float* __restrict__ x_out)
{
    int e = blockIdx.x * 256 + threadIdx.x;
    if (e >= kE) return;
    int s = src[e];
    int d = dst[e];
    float w = ew[e];
#pragma unroll
    for (int c = 0; c < 3; ++c)
        atomicAdd(&x_out[(long)d * 3 + c], w * sup2[(long)s * 3 + c]);
}

// ---------------------------------------------------------------------------
extern "C" void kernel_launch(void* const* d_in, const int* in_sizes, int n_in,
                              void* d_out, int out_size, void* d_ws, size_t ws_size,
                              hipStream_t stream)
{
    const float* x    = (const float*)d_in[0];
    const int*   src  = (const int*)d_in[1];
    const int*   dst  = (const int*)d_in[2];
    const float* ew   = (const float*)d_in[3];
    const float* W1   = (const float*)d_in[4];
    const float* Wl1  = (const float*)d_in[5];
    const float* b1   = (const float*)d_in[6];
    const float* blkW  = (const float*)d_in[7];
    const float* blkWl = (const float*)d_in[8];
    const float* blkb  = (const float*)d_in[9];
    const float* W2   = (const float*)d_in[10];
    const float* Wl2  = (const float*)d_in[11];
    const float* b2   = (const float*)d_in[12];

    float* out   = (float*)d_out;
    float* x_out = out;                       // N*3
    float* h     = out + (long)kN * 3;        // N*H fp32 = x_hidden output

    // ---- workspace carve-up
    char* w = (char*)d_ws;
    size_t off = 0;
    auto carve = [&](size_t bytes) { char* p = w + off; off = (off + bytes + 255) & ~(size_t)255; return p; };
    unsigned short* supb  = (unsigned short*)carve(12800000UL * 2);
    unsigned short* tpreb = (unsigned short*)carve(12800000UL * 2);  // layer-1 only
    unsigned short* tact  = (unsigned short*)carve(12800000UL * 2);
    unsigned short* hbf   = (unsigned short*)carve(12800000UL * 2);
    unsigned short* w1c   = (unsigned short*)carve(512UL * 1024 * 2);
    unsigned short* blkc  = (unsigned short*)carve(12UL * 256 * 512 * 2);
    int*   e_src  = (int*)carve(kE * 4);
    float* e_w    = (float*)carve(kE * 4);
    int*   counts = (int*)carve(50176 * 4);
    int*   rowptr = (int*)carve(50176 * 4);
    int*   cursor = (int*)carve(50176 * 4);
    int*   bsum   = (int*)carve(64 * 4);
    float* sup2   = (float*)carve((long)kN * 3 * 4);
    unsigned short* xagg = tpreb;             // alias: tpreb dead after agg_l1

    // ---- CSR build
    hipMemsetAsync(counts, 0, 50176 * 4, stream);
    hist_kernel<<<(kE + 255) / 256, 256, 0, stream>>>(dst, counts);
    scan1_kernel<<<49, 1024, 0, stream>>>(counts, rowptr, bsum);
    scan2_kernel<<<1, 64, 0, stream>>>(bsum, 49);
    scan3_kernel<<<(kN + 255) / 256, 256, 0, stream>>>(rowptr, bsum, cursor);
    fill_kernel<<<(kE + 255) / 256, 256, 0, stream>>>(src, dst, ew, cursor, e_src, e_w);

    // ---- weight conversion
    cvt_w1_kernel<<<2048, 256, 0, stream>>>(W1, Wl1, w1c);
    cvt_blk_kernel<<<6144, 256, 0, stream>>>(blkW, blkWl, blkc);

    const int l1_grid  = (kN + 127) / 128;         // 391 (both col-halves/block)
    const int blk_grid = 2 * ((kN + 127) / 128);   // 782 (2 col-tiles of 128)
    const int agg_grid = (kN + 7) / 8;             // 6250

    // ---- Layer 1: hbf = bf16(relu(gconv(x)))
    gemm_l1<<<l1_grid, 512, 0, stream>>>(x, w1c, b1, supb, tpreb,
                                         kN, 1024, kDIN, kDIN);
    agg16_kernel<1><<<agg_grid, 256, 0, stream>>>(supb, tpreb, rowptr, e_src, e_w, hbf);

    // ---- 12 block convs (linearity order: agg-first, K=512 fused GEMM)
    for (int l = 0; l < 2 * kNBLK; ++l) {
        const unsigned short* act_in = (l & 1) ? tact : hbf;
        unsigned short* act_out      = (l & 1) ? hbf : tact;
        agg16_kernel<0><<<agg_grid, 256, 0, stream>>>(act_in, nullptr, rowptr, e_src, e_w, xagg);
        const unsigned short* B = blkc + (long)l * 256 * 512;
        const float* bb = blkb + (long)l * 256;
        if (l & 1) {
            if (l == 2 * kNBLK - 1)
                gemm_blk<2><<<blk_grid, 256, 0, stream>>>(act_in, xagg, B, bb, hbf, act_out, h);
            else
                gemm_blk<1><<<blk_grid, 256, 0, stream>>>(act_in, xagg, B, bb, hbf, act_out, nullptr);
        } else {
            gemm_blk<0><<<blk_grid, 256, 0, stream>>>(act_in, xagg, B, bb, nullptr, act_out, nullptr);
        }
    }

    // ---- final layer
    final_layer_kernel<<<kN, 64, 0, stream>>>(hbf, W2, Wl2, b2, sup2, x_out);
    scatter3_kernel<<<(kE + 255) / 256, 256, 0, stream>>>(sup2, src, dst, ew, x_out);
}